// Round 1
// baseline (336.356 us; speedup 1.0000x reference)
//
#include <hip/hip_runtime.h>

// Multi-scale gradient-difference loss as line-parallel reductions.
// R7: single fused kernel (pass1 -> software grid barrier -> pass2 -> final).
// Rationale: rocprof top-5 shows both old kernels < 40us each, so a large
// slice of the 128us was structure: pass2's full line re-stage (the V/diag
// gathers are uncoalesced and were done TWICE), two launch boundaries, and
// the separate final kernel. Fusing keeps the staged line in LDS across the
// barrier and removes all of that.
// Residency proof for the software barrier: __launch_bounds__(256,8) forces
// <=64 VGPR -> 8 waves/SIMD; LDS 10.4KB/block -> 8 blocks/CU (83KB of 160KB);
// grid 2046 <= 256 CU * 8 = 2048 co-resident. Spins are bounded so a
// residency surprise fails loudly instead of hanging the harness.

#define NSCALES 67
#define IMG_H 256
#define IMG_W 256
#define NPIX 65536
#define NLINES 2046          // 512 rows (H) + 512 cols (V) + 1022 diagonals (D)
#define LMAX_PAD 320         // 256 positions + 64 zero pad (max tap index 318)

// ws layout (doubles):
//  [0..3] b0 {S1,S2,posCnt,sumAbsPrd}  [4..7] b1 same
//  [8..9] roiSum[b]   [16] barrier counter (int in low word)   [24..25] T1[b]

__device__ __forceinline__ double wave_red(double v) {
#pragma unroll
  for (int o = 32; o > 0; o >>= 1) v += __shfl_down(v, o, 64);
  return v;
}

__device__ __forceinline__ void decode_line(int id, int& b, int& base, int& stride, int& L) {
  if (id < 512) {                      // horizontal row
    b = id >> 8; int y = id & 255;
    base = y * IMG_W; stride = 1; L = IMG_W;
  } else if (id < 1024) {              // vertical column
    int t = id - 512; b = t >> 8;
    base = t & 255; stride = IMG_W; L = IMG_H;
  } else {                             // diagonal c = x - y in [-255,255]
    int t = id - 1024; b = (t >= 511) ? 1 : 0;
    int d = t - b * 511; int c = d - 255;
    int ac = (c < 0) ? -c : c;
    base = (c < 0) ? (-c) * IMG_W : c;
    stride = IMG_W + 1; L = 256 - ac;
  }
}

// #scales valid for quarter q (centers [64q, 64q+63]): s = 1+3k <= min(L-1-64q, 199)
__device__ __forceinline__ int scale_count(int L, int q) {
  int rem = L - 1 - (q << 6);
  int kcnt = (rem >= 1) ? ((rem - 1) / 3 + 1) : 0;
  return (kcnt > NSCALES) ? NSCALES : kcnt;
}

// Stage line; returns this tid's ROI value (position tid) for the ROI sum.
__device__ __forceinline__ float stage_line(
    const float* __restrict__ Pred, const float* __restrict__ GT,
    const float* __restrict__ ROI, int b, int base, int stride, int L,
    int tid, float4* bufA, float4* bufB) {
  const float* P = Pred + b * (3 * NPIX);
  const float* G = GT + b * (3 * NPIX);
  const float* R = ROI + b * NPIX;
  float r = 0.f, p0 = 0.f, p1 = 0.f, p2 = 0.f, g0 = 0.f, g1 = 0.f, g2 = 0.f;
  if (tid < L) {
    int a = base + tid * stride;
    r = R[a];
    p0 = P[a]; p1 = P[a + NPIX]; p2 = P[a + 2 * NPIX];
    g0 = G[a]; g1 = G[a + NPIX]; g2 = G[a + 2 * NPIX];
  }
  bufA[tid] = make_float4(r, p0, p1, p2);
  bufB[tid] = make_float4(g0, g1, g2, 0.f);
  if (tid < LMAX_PAD - 256) {
    bufA[256 + tid] = make_float4(0.f, 0.f, 0.f, 0.f);
    bufB[256 + tid] = make_float4(0.f, 0.f, 0.f, 0.f);
  }
  __syncthreads();
  return r;
}

// Device-scope coherent read: per-XCD L2s are not cross-coherent, so after
// the software barrier a plain load could be stale. Agent-scope atomic load
// reads at the coherent point (same one the unsafeAtomicAdds landed at).
__device__ __forceinline__ double aread(const double* p) {
  return __hip_atomic_load(p, __ATOMIC_RELAXED, __HIP_MEMORY_SCOPE_AGENT);
}

extern "C" __global__ void __launch_bounds__(256, 8) fused_kernel(
    const float* __restrict__ Pred, const float* __restrict__ GT,
    const float* __restrict__ ROI, double* __restrict__ ws,
    float* __restrict__ out) {
  __shared__ float4 bufA[LMAX_PAD];    // {r, p0, p1, p2}
  __shared__ float4 bufB[LMAX_PAD];    // {g0, g1, g2, 0}
  __shared__ double red[4][5];
  __shared__ float s_invC;
  const int id = blockIdx.x;
  const int tid = threadIdx.x;
  const int wid = tid >> 6, lane = tid & 63;

  int b, base, stride, L;
  decode_line(id, b, base, stride, L);
  float stg_r = stage_line(Pred, GT, ROI, b, base, stride, L, tid, bufA, bufB);

  // ---------------- pass 1: S1, S2, posCnt, sumAbsPrd, roiSum ----------------
  float f1 = 0.f, f2 = 0.f, fp = 0.f;
  int pci = 0;
  int P = 0;                            // task prefix
  for (int q = 0; q < 4; ++q) {
    const int Kq = scale_count(L, q);
    int k = (wid - P) & 3;              // round-robin task deal across 4 waves
    if (k < Kq) {
      const int c = (q << 6) + lane;
      const float4 cA = bufA[c];
      const float4 cB = bufB[c];
      const float cr = cA.x, cp0 = cA.y, cp1 = cA.z, cp2 = cA.w;
      const float cg0 = cB.x, cg1 = cB.y, cg2 = cB.z;
      const float4* tA = &bufA[c + 1 + 3 * k];
      const float4* tB = &bufB[c + 1 + 3 * k];
#pragma unroll 2
      for (; k < Kq; k += 4) {
        float4 t0 = tA[0];
        float4 t1 = tB[0];
        tA += 12; tB += 12;             // s += 12
        float rr = cr * t0.x;
#define L1BODY(cp, cg, tp, tg)                                   \
        {                                                        \
          float dP = rr * (cp - tp);                             \
          float dG = rr * (cg - tg);                             \
          float qq = dP * __builtin_amdgcn_rcpf(dG + 1e-5f);     \
          float aG = fabsf(dG);                                  \
          f1 += fmaxf(aG * qq, 0.f);                             \
          if (qq > 0.f) f2 += aG;                                \
          if (dG > 0.f) pci++;                                   \
          fp += fabsf(dP);                                       \
        }
        L1BODY(cp0, cg0, t0.y, t1.x)
        L1BODY(cp1, cg1, t0.z, t1.y)
        L1BODY(cp2, cg2, t0.w, t1.z)
#undef L1BODY
      }
    }
    P += Kq;
  }

  double w0 = wave_red((double)f1);
  double w1 = wave_red((double)f2);
  double w2 = wave_red((double)pci);
  double w3 = wave_red((double)fp);
  double w4 = wave_red((double)stg_r);  // ROI partial: position tid, once/block
  if (lane == 0) {
    red[wid][0] = w0; red[wid][1] = w1; red[wid][2] = w2;
    red[wid][3] = w3; red[wid][4] = w4;
  }
  __syncthreads();
  if (tid < 4)
    unsafeAtomicAdd(&ws[b * 4 + tid],
                    red[0][tid] + red[1][tid] + red[2][tid] + red[3][tid]);
  if (tid == 4 && id < 512)             // H rows tile the image exactly once
    unsafeAtomicAdd(&ws[8 + b], red[0][4] + red[1][4] + red[2][4] + red[3][4]);

  // ---------------- software grid barrier #1 ----------------
  int* ctr = (int*)&ws[16];
  __threadfence();                      // release this block's atomics
  __syncthreads();
  if (tid == 0) {
    __hip_atomic_fetch_add(ctr, 1, __ATOMIC_ACQ_REL, __HIP_MEMORY_SCOPE_AGENT);
    int spins = 0;                      // bounded: fail loudly, never hang
    while (__hip_atomic_load(ctr, __ATOMIC_ACQUIRE, __HIP_MEMORY_SCOPE_AGENT) < NLINES &&
           spins < (1 << 22)) {
      __builtin_amdgcn_s_sleep(2);
      ++spins;
    }
    double S1 = aread(&ws[b * 4 + 0]), S2 = aread(&ws[b * 4 + 1]);
    float cc = (float)(S1 / (S2 + 1e-4));
    s_invC = (cc > 1e-4f) ? (float)(1.0 / (double)cc) : 1.0f;
  }
  __syncthreads();

  // ---------------- pass 2: T1 (line still staged in LDS) ----------------
  const float invC = s_invC;
  float f = 0.f;
  P = 0;
  for (int q = 0; q < 4; ++q) {
    const int Kq = scale_count(L, q);
    int k = (wid - P) & 3;
    if (k < Kq) {
      const int c = (q << 6) + lane;
      const float4 cA = bufA[c];
      const float4 cB = bufB[c];
      const float cr = cA.x, cp0 = cA.y, cp1 = cA.z, cp2 = cA.w;
      const float cg0 = cB.x, cg1 = cB.y, cg2 = cB.z;
      const float4* tA = &bufA[c + 1 + 3 * k];
      const float4* tB = &bufB[c + 1 + 3 * k];
#pragma unroll 2
      for (; k < Kq; k += 4) {
        float4 t0 = tA[0];
        float4 t1 = tB[0];
        tA += 12; tB += 12;
        float rr = cr * t0.x;
        // |difGT - difPrd/c| = rr * |(g-gt) - (p-pt)*invC|   (rr in {0,1})
        f += rr * fabsf((cg0 - t1.x) - (cp0 - t0.y) * invC);
        f += rr * fabsf((cg1 - t1.y) - (cp1 - t0.z) * invC);
        f += rr * fabsf((cg2 - t1.z) - (cp2 - t0.w) * invC);
      }
    }
    P += Kq;
  }
  double t = wave_red((double)f);
  if (lane == 0) red[wid][0] = t;
  __syncthreads();
  if (tid == 0) {
    unsafeAtomicAdd(&ws[24 + b], red[0][0] + red[1][0] + red[2][0] + red[3][0]);
    __threadfence();                    // release T1 before arriving
    __hip_atomic_fetch_add(ctr, 1, __ATOMIC_ACQ_REL, __HIP_MEMORY_SCOPE_AGENT);
  }

  // ---------------- final: block 0 only (others exit, arrive-only) ----------
  if (id == 0 && tid == 0) {
    int spins = 0;
    while (__hip_atomic_load(ctr, __ATOMIC_ACQUIRE, __HIP_MEMORY_SCOPE_AGENT) < 2 * NLINES &&
           spins < (1 << 22)) {
      __builtin_amdgcn_s_sleep(2);
      ++spins;
    }
    double loss = 0.0;
    for (int bb = 0; bb < 2; ++bb) {
      double S1 = aread(&ws[bb * 4 + 0]), S2 = aread(&ws[bb * 4 + 1]);
      double PC = aread(&ws[bb * 4 + 2]), SP = aread(&ws[bb * 4 + 3]);
      double RS = aread(&ws[8 + bb]);
      float cc = (float)(S1 / (S2 + 1e-4));
      out[1 + bb] = cc;                 // NormConst
      double term1 = (cc > 1e-4f) ? aread(&ws[24 + bb]) / (603.0 * 65536.0) : 0.0;
      float meanPrd = (float)(SP / PC);
      bool big = RS > 200.0;
      float t2 = (big && meanPrd > 30.f && cc > 10.f) ? (meanPrd - 30.f) : 0.f;
      float fact = 0.1f / (cc + 0.001f);
      float t3 = (big && meanPrd < 2.f && cc < 0.1f) ? (0.2f - meanPrd) * fact : 0.f;
      loss += term1 + (double)(t2 + t3);
    }
    out[0] = (float)loss;
  }
}

extern "C" void kernel_launch(void* const* d_in, const int* in_sizes, int n_in,
                              void* d_out, int out_size, void* d_ws, size_t ws_size,
                              hipStream_t stream) {
  (void)in_sizes; (void)n_in; (void)out_size; (void)ws_size;
  const float* Pred = (const float*)d_in[0];
  const float* GT = (const float*)d_in[1];
  const float* ROI = (const float*)d_in[2];
  float* out = (float*)d_out;
  double* ws = (double*)d_ws;

  hipMemsetAsync(d_ws, 0, 32 * sizeof(double), stream);   // zero accums + ctr
  hipLaunchKernelGGL(fused_kernel, dim3(NLINES), dim3(256), 0, stream,
                     Pred, GT, ROI, ws, out);
}

// Round 2
// 160.027 us; speedup vs baseline: 2.1019x; 2.1019x over previous
//
#include <hip/hip_runtime.h>

// Multi-scale gradient-difference loss as line-parallel reductions.
// R8: revert R7's fused grid-barrier (283us kernel, VALUBusy 12% -- the
// 2046-block spin on one agent-scope counter serialized at the coherent
// point). Back to two launches, plus two structural fixes:
//  1) CU load balance: grid=1024 persistent blocks. Block i statically takes
//     line i (ids 0..1023 are the uniform-weight H/V lines), then pops
//     diagonal lines (the variable-weight fillers, ids 1024..2045) from a
//     global atomic queue. LPT-style balance independent of HW placement.
//  2) final_kernel folded into pass2 via last-block-done: one fetch_add per
//     block (no spinning); rank GRID1-1 computes the loss. Cross-block
//     visibility via threadfence + acq_rel counter was HW-validated in R7
//     (absmax 0.0 there).

#define NSCALES 67
#define IMG_H 256
#define IMG_W 256
#define NPIX 65536
#define NLINES 2046          // 512 rows (H) + 512 cols (V) + 1022 diagonals (D)
#define LMAX_PAD 320         // 256 positions + 64 zero pad (max tap index 318)
#define GRID1 1024           // persistent blocks; ids 0..1023 = the H/V lines

// ws layout (doubles):
//  [0..3] b0 {S1,S2,posCnt,sumAbsPrd}  [4..7] b1 same
//  [8..9] roiSum[b]
//  [16] pass1 queue ctr (int)  [17] pass2 queue ctr (int)  [18] done ctr (int)
//  [24..25] T1[b]

__device__ __forceinline__ double wave_red(double v) {
#pragma unroll
  for (int o = 32; o > 0; o >>= 1) v += __shfl_down(v, o, 64);
  return v;
}

__device__ __forceinline__ void decode_line(int id, int& b, int& base, int& stride, int& L) {
  if (id < 512) {                      // horizontal row
    b = id >> 8; int y = id & 255;
    base = y * IMG_W; stride = 1; L = IMG_W;
  } else if (id < 1024) {              // vertical column
    int t = id - 512; b = t >> 8;
    base = t & 255; stride = IMG_W; L = IMG_H;
  } else {                             // diagonal c = x - y in [-255,255]
    int t = id - 1024; b = (t >= 511) ? 1 : 0;
    int d = t - b * 511; int c = d - 255;
    int ac = (c < 0) ? -c : c;
    base = (c < 0) ? (-c) * IMG_W : c;
    stride = IMG_W + 1; L = 256 - ac;
  }
}

// #scales valid for quarter q (centers [64q, 64q+63]): s = 1+3k <= min(L-1-64q, 199)
__device__ __forceinline__ int scale_count(int L, int q) {
  int rem = L - 1 - (q << 6);
  int kcnt = (rem >= 1) ? ((rem - 1) / 3 + 1) : 0;
  return (kcnt > NSCALES) ? NSCALES : kcnt;
}

// Stage line; returns this tid's ROI value (position tid) for the ROI sum.
__device__ __forceinline__ float stage_line(
    const float* __restrict__ Pred, const float* __restrict__ GT,
    const float* __restrict__ ROI, int b, int base, int stride, int L,
    int tid, float4* bufA, float4* bufB) {
  const float* P = Pred + b * (3 * NPIX);
  const float* G = GT + b * (3 * NPIX);
  const float* R = ROI + b * NPIX;
  float r = 0.f, p0 = 0.f, p1 = 0.f, p2 = 0.f, g0 = 0.f, g1 = 0.f, g2 = 0.f;
  if (tid < L) {
    int a = base + tid * stride;
    r = R[a];
    p0 = P[a]; p1 = P[a + NPIX]; p2 = P[a + 2 * NPIX];
    g0 = G[a]; g1 = G[a + NPIX]; g2 = G[a + 2 * NPIX];
  }
  bufA[tid] = make_float4(r, p0, p1, p2);
  bufB[tid] = make_float4(g0, g1, g2, 0.f);
  if (tid < LMAX_PAD - 256) {
    bufA[256 + tid] = make_float4(0.f, 0.f, 0.f, 0.f);
    bufB[256 + tid] = make_float4(0.f, 0.f, 0.f, 0.f);
  }
  __syncthreads();
  return r;
}

__device__ __forceinline__ double aread(const double* p) {
  return __hip_atomic_load(p, __ATOMIC_RELAXED, __HIP_MEMORY_SCOPE_AGENT);
}

extern "C" __global__ void __launch_bounds__(256, 8) pass1_kernel(
    const float* __restrict__ Pred, const float* __restrict__ GT,
    const float* __restrict__ ROI, double* __restrict__ ws) {
  __shared__ float4 bufA[LMAX_PAD];    // {r, p0, p1, p2}
  __shared__ float4 bufB[LMAX_PAD];    // {g0, g1, g2, 0}
  __shared__ double red[4][5];
  __shared__ int s_line;
  const int tid = threadIdx.x;
  const int wid = tid >> 6, lane = tid & 63;
  int* ctr = (int*)&ws[16];

  int id = blockIdx.x;                  // static first line: the H/V lines
  while (id < NLINES) {
    int b, base, stride, L;
    decode_line(id, b, base, stride, L);
    float stg_r = stage_line(Pred, GT, ROI, b, base, stride, L, tid, bufA, bufB);

    float f1 = 0.f, f2 = 0.f, fp = 0.f;
    int pci = 0;
    int P = 0;                          // task prefix
    for (int q = 0; q < 4; ++q) {
      const int Kq = scale_count(L, q);
      int k = (wid - P) & 3;            // round-robin task deal across 4 waves
      if (k < Kq) {
        const int c = (q << 6) + lane;
        const float4 cA = bufA[c];
        const float4 cB = bufB[c];
        const float cr = cA.x, cp0 = cA.y, cp1 = cA.z, cp2 = cA.w;
        const float cg0 = cB.x, cg1 = cB.y, cg2 = cB.z;
        const float4* tA = &bufA[c + 1 + 3 * k];
        const float4* tB = &bufB[c + 1 + 3 * k];
#pragma unroll 2
        for (; k < Kq; k += 4) {
          float4 t0 = tA[0];
          float4 t1 = tB[0];
          tA += 12; tB += 12;           // s += 12
          float rr = cr * t0.x;
#define L1BODY(cp, cg, tp, tg)                                   \
          {                                                      \
            float dP = rr * (cp - tp);                           \
            float dG = rr * (cg - tg);                           \
            float qq = dP * __builtin_amdgcn_rcpf(dG + 1e-5f);   \
            float aG = fabsf(dG);                                \
            f1 += fmaxf(aG * qq, 0.f);                           \
            if (qq > 0.f) f2 += aG;                              \
            if (dG > 0.f) pci++;                                 \
            fp += fabsf(dP);                                     \
          }
          L1BODY(cp0, cg0, t0.y, t1.x)
          L1BODY(cp1, cg1, t0.z, t1.y)
          L1BODY(cp2, cg2, t0.w, t1.z)
#undef L1BODY
        }
      }
      P += Kq;
    }

    double w0 = wave_red((double)f1);
    double w1 = wave_red((double)f2);
    double w2 = wave_red((double)pci);
    double w3 = wave_red((double)fp);
    double w4 = wave_red((double)stg_r);  // ROI partial: once per line
    if (lane == 0) {
      red[wid][0] = w0; red[wid][1] = w1; red[wid][2] = w2;
      red[wid][3] = w3; red[wid][4] = w4;
    }
    __syncthreads();
    if (tid < 4)
      unsafeAtomicAdd(&ws[b * 4 + tid],
                      red[0][tid] + red[1][tid] + red[2][tid] + red[3][tid]);
    if (tid == 4 && id < 512)           // H rows tile the image exactly once
      unsafeAtomicAdd(&ws[8 + b], red[0][4] + red[1][4] + red[2][4] + red[3][4]);

    // pop next diagonal line (no spin; queue starts at id 1024)
    __syncthreads();                    // epilogue done before buf/s_line reuse
    if (tid == 0)
      s_line = 1024 + __hip_atomic_fetch_add(ctr, 1, __ATOMIC_RELAXED,
                                             __HIP_MEMORY_SCOPE_AGENT);
    __syncthreads();
    id = s_line;
  }
}

extern "C" __global__ void __launch_bounds__(256, 8) pass2_kernel(
    const float* __restrict__ Pred, const float* __restrict__ GT,
    const float* __restrict__ ROI, double* __restrict__ ws,
    float* __restrict__ out) {
  __shared__ float4 bufA[LMAX_PAD];
  __shared__ float4 bufB[LMAX_PAD];
  __shared__ double red[4];
  __shared__ float s_invC[2];
  __shared__ int s_line;
  const int tid = threadIdx.x;
  const int wid = tid >> 6, lane = tid & 63;
  int* ctr = (int*)&ws[17];
  int* done = (int*)&ws[18];

  if (tid < 2) {                        // invC per batch; pass1 sums are
    double S1 = ws[tid * 4 + 0];        // coherent across the kernel boundary
    double S2 = ws[tid * 4 + 1];
    float cc = (float)(S1 / (S2 + 1e-4));
    s_invC[tid] = (cc > 1e-4f) ? (float)(1.0 / (double)cc) : 1.0f;
  }
  __syncthreads();

  int id = blockIdx.x;
  while (id < NLINES) {
    int b, base, stride, L;
    decode_line(id, b, base, stride, L);
    stage_line(Pred, GT, ROI, b, base, stride, L, tid, bufA, bufB);

    const float invC = s_invC[b];
    float f = 0.f;
    int P = 0;
    for (int q = 0; q < 4; ++q) {
      const int Kq = scale_count(L, q);
      int k = (wid - P) & 3;
      if (k < Kq) {
        const int c = (q << 6) + lane;
        const float4 cA = bufA[c];
        const float4 cB = bufB[c];
        const float cr = cA.x, cp0 = cA.y, cp1 = cA.z, cp2 = cA.w;
        const float cg0 = cB.x, cg1 = cB.y, cg2 = cB.z;
        const float4* tA = &bufA[c + 1 + 3 * k];
        const float4* tB = &bufB[c + 1 + 3 * k];
#pragma unroll 2
        for (; k < Kq; k += 4) {
          float4 t0 = tA[0];
          float4 t1 = tB[0];
          tA += 12; tB += 12;
          float rr = cr * t0.x;
          // |difGT - difPrd/c| = rr * |(g-gt) - (p-pt)*invC|   (rr in {0,1})
          f += rr * fabsf((cg0 - t1.x) - (cp0 - t0.y) * invC);
          f += rr * fabsf((cg1 - t1.y) - (cp1 - t0.z) * invC);
          f += rr * fabsf((cg2 - t1.z) - (cp2 - t0.w) * invC);
        }
      }
      P += Kq;
    }
    double t = wave_red((double)f);
    if (lane == 0) red[wid] = t;
    __syncthreads();
    if (tid == 0)
      unsafeAtomicAdd(&ws[24 + b], red[0] + red[1] + red[2] + red[3]);

    __syncthreads();
    if (tid == 0)
      s_line = 1024 + __hip_atomic_fetch_add(ctr, 1, __ATOMIC_RELAXED,
                                             __HIP_MEMORY_SCOPE_AGENT);
    __syncthreads();
    id = s_line;
  }

  // last-block-done: rank GRID1-1 computes the final loss (no spinning)
  if (tid == 0) {
    __threadfence();                    // release this block's T1 adds
    int rank = __hip_atomic_fetch_add(done, 1, __ATOMIC_ACQ_REL,
                                      __HIP_MEMORY_SCOPE_AGENT);
    if (rank == GRID1 - 1) {
      double loss = 0.0;
      for (int bb = 0; bb < 2; ++bb) {
        double S1 = aread(&ws[bb * 4 + 0]), S2 = aread(&ws[bb * 4 + 1]);
        double PC = aread(&ws[bb * 4 + 2]), SP = aread(&ws[bb * 4 + 3]);
        double RS = aread(&ws[8 + bb]);
        float cc = (float)(S1 / (S2 + 1e-4));
        out[1 + bb] = cc;               // NormConst
        double term1 = (cc > 1e-4f) ? aread(&ws[24 + bb]) / (603.0 * 65536.0) : 0.0;
        float meanPrd = (float)(SP / PC);
        bool big = RS > 200.0;
        float t2 = (big && meanPrd > 30.f && cc > 10.f) ? (meanPrd - 30.f) : 0.f;
        float fact = 0.1f / (cc + 0.001f);
        float t3 = (big && meanPrd < 2.f && cc < 0.1f) ? (0.2f - meanPrd) * fact : 0.f;
        loss += term1 + (double)(t2 + t3);
      }
      out[0] = (float)loss;
    }
  }
}

extern "C" void kernel_launch(void* const* d_in, const int* in_sizes, int n_in,
                              void* d_out, int out_size, void* d_ws, size_t ws_size,
                              hipStream_t stream) {
  (void)in_sizes; (void)n_in; (void)out_size; (void)ws_size;
  const float* Pred = (const float*)d_in[0];
  const float* GT = (const float*)d_in[1];
  const float* ROI = (const float*)d_in[2];
  float* out = (float*)d_out;
  double* ws = (double*)d_ws;

  hipMemsetAsync(d_ws, 0, 32 * sizeof(double), stream);   // accums + ctrs
  hipLaunchKernelGGL(pass1_kernel, dim3(GRID1), dim3(256), 0, stream,
                     Pred, GT, ROI, ws);
  hipLaunchKernelGGL(pass2_kernel, dim3(GRID1), dim3(256), 0, stream,
                     Pred, GT, ROI, ws, out);
}